// Round 1
// baseline (1334.762 us; speedup 1.0000x reference)
//
#include <hip/hip_runtime.h>
#include <hip/hip_bf16.h>
#include <float.h>

#define BATCH 4
#define NPTS  4096
#define BN    16384      // BATCH*NPTS
#define KNN   16
#define DIN   64
#define DT    128

// ---------------------------------------------------------------- sq kernel
__global__ __launch_bounds__(256) void sq_kernel(const float* __restrict__ pos,
                                                 float* __restrict__ sq) {
    int i = blockIdx.x * 256 + threadIdx.x;
    if (i < BN) {
        float p0 = pos[i*3+0], p1 = pos[i*3+1], p2 = pos[i*3+2];
        sq[i] = fmaf(p2, p2, fmaf(p1, p1, p0*p0));
    }
}

// ---------------------------------------------------------------- knn kernel
// one wave (64 threads) per query point. Each lane keeps a sorted top-16 of its
// strided candidate subset in registers, then a 16-round shuffle merge selects
// the global top-16 in ascending (dist, idx) order == stable argsort[:16].
__global__ __launch_bounds__(64) void knn_kernel(const float* __restrict__ pos,
                                                 const float* __restrict__ sq,
                                                 int* __restrict__ knn) {
    int n = blockIdx.x;          // absolute point id
    int base = (n >> 12) << 12;  // batch base
    int t = threadIdx.x;

    float px = pos[n*3+0], py = pos[n*3+1], pz = pos[n*3+2];
    float sn = sq[n];

    float d[16]; int id[16];
#pragma unroll
    for (int i = 0; i < 16; i++) { d[i] = FLT_MAX; id[i] = 0x7fffffff; }

    for (int m = t; m < NPTS; m += 64) {
        int j = base + m;
        float qx = pos[j*3+0], qy = pos[j*3+1], qz = pos[j*3+2];
        float dot  = fmaf(pz, qz, fmaf(py, qy, px*qx));
        float dist = (sn + sq[j]) - 2.0f * dot;
        if (dist < d[15] || (dist == d[15] && j < id[15])) {
            float cd = dist; int ci = j;
#pragma unroll
            for (int i = 0; i < 16; i++) {
                bool lt = (cd < d[i]) || (cd == d[i] && ci < id[i]);
                float td = lt ? d[i]  : cd;  int ti = lt ? id[i] : ci;
                d[i]  = lt ? cd : d[i];
                id[i] = lt ? ci : id[i];
                cd = td; ci = ti;
            }
        }
    }

    __shared__ float sd[64*16];
    __shared__ int   si[64*16];
#pragma unroll
    for (int i = 0; i < 16; i++) { sd[t*16+i] = d[i]; si[t*16+i] = id[i]; }
    __syncthreads();

    int p = 0;
    for (int r = 0; r < 16; r++) {
        float hd = (p < 16) ? sd[t*16+p] : FLT_MAX;
        int   hi = (p < 16) ? si[t*16+p] : 0x7fffffff;
        float bd = hd; int bi = hi;
        for (int off = 32; off > 0; off >>= 1) {
            float od = __shfl_xor(bd, off, 64);
            int   oi = __shfl_xor(bi, off, 64);
            if (od < bd || (od == bd && oi < bi)) { bd = od; bi = oi; }
        }
        if (p < 16 && hi == bi) p++;
        if (t == 0) knn[n*16 + r] = bi;   // absolute index
    }
}

// ---------------------------------------------------------------- feat kernel
// h = x@fc1+b ; q = h@wq ; kf = h@wk ; vf = h@wv.  16 rows per block,
// register-tiled: thread owns 2 rows x 4 features.
__global__ __launch_bounds__(256) void feat_kernel(
    const float* __restrict__ x,
    const float* __restrict__ fc1w, const float* __restrict__ fc1b,
    const float* __restrict__ wq, const float* __restrict__ wk,
    const float* __restrict__ wv,
    float* __restrict__ q, float* __restrict__ kf, float* __restrict__ vf) {
    __shared__ float xs[16][64];
    __shared__ float hs[16][128];
    int rb = blockIdx.x * 16;
    int t  = threadIdx.x;

    for (int i = t; i < 16*64; i += 256) xs[i>>6][i&63] = x[rb*64 + i];
    __syncthreads();

    int f4 = (t & 31) * 4;
    int r0 = (t >> 5) * 2, r1 = r0 + 1;
    float a0[4], a1[4];
#pragma unroll
    for (int jf = 0; jf < 4; jf++) { a0[jf] = fc1b[f4+jf]; a1[jf] = fc1b[f4+jf]; }
#pragma unroll 4
    for (int c = 0; c < 64; c += 4) {
        float s0[4], s1[4];
        *(float4*)s0 = *(const float4*)&xs[r0][c];
        *(float4*)s1 = *(const float4*)&xs[r1][c];
#pragma unroll
        for (int jc = 0; jc < 4; jc++) {
            float w[4];
            *(float4*)w = *(const float4*)&fc1w[(c+jc)*128 + f4];
#pragma unroll
            for (int jf = 0; jf < 4; jf++) {
                a0[jf] = fmaf(s0[jc], w[jf], a0[jf]);
                a1[jf] = fmaf(s1[jc], w[jf], a1[jf]);
            }
        }
    }
    *(float4*)&hs[r0][f4] = *(float4*)a0;
    *(float4*)&hs[r1][f4] = *(float4*)a1;
    __syncthreads();

    const float* Ws[3] = { wq, wk, wv };
    float*       Os[3] = { q, kf, vf };
    for (int mtx = 0; mtx < 3; mtx++) {
        const float* __restrict__ W = Ws[mtx];
#pragma unroll
        for (int jf = 0; jf < 4; jf++) { a0[jf] = 0.f; a1[jf] = 0.f; }
#pragma unroll 4
        for (int c = 0; c < 128; c += 4) {
            float s0[4], s1[4];
            *(float4*)s0 = *(const float4*)&hs[r0][c];
            *(float4*)s1 = *(const float4*)&hs[r1][c];
#pragma unroll
            for (int jc = 0; jc < 4; jc++) {
                float w[4];
                *(float4*)w = *(const float4*)&W[(c+jc)*128 + f4];
#pragma unroll
                for (int jf = 0; jf < 4; jf++) {
                    a0[jf] = fmaf(s0[jc], w[jf], a0[jf]);
                    a1[jf] = fmaf(s1[jc], w[jf], a1[jf]);
                }
            }
        }
        float* O = Os[mtx];
        *(float4*)&O[(size_t)(rb+r0)*128 + f4] = *(float4*)a0;
        *(float4*)&O[(size_t)(rb+r1)*128 + f4] = *(float4*)a1;
    }
}

// ---------------------------------------------------------------- main kernel
// Block per query point. LDS buffers (16x128):
//  B1: (q - k_gather) -> a -> gm -> attn ;  B2: v + pos_enc ;  B3: hd -> gh
// pos_enc lives only in registers (thread owns rows k0,k1 x feats f4..f4+3).
__device__ __forceinline__ void dot128x2(const float* s0p, const float* s1p,
                                         const float* __restrict__ W, int f4,
                                         float a0[4], float a1[4]) {
#pragma unroll 4
    for (int c = 0; c < 128; c += 4) {
        float s0[4], s1[4];
        *(float4*)s0 = *(const float4*)(s0p + c);
        *(float4*)s1 = *(const float4*)(s1p + c);
#pragma unroll
        for (int jc = 0; jc < 4; jc++) {
            float w[4];
            *(float4*)w = *(const float4*)&W[(c+jc)*128 + f4];
#pragma unroll
            for (int jf = 0; jf < 4; jf++) {
                a0[jf] = fmaf(s0[jc], w[jf], a0[jf]);
                a1[jf] = fmaf(s1[jc], w[jf], a1[jf]);
            }
        }
    }
}

__global__ __launch_bounds__(256) void main_kernel(
    const float* __restrict__ pos, const float* __restrict__ x,
    const float* __restrict__ q, const float* __restrict__ kf,
    const float* __restrict__ vf, const int* __restrict__ knn,
    const float* __restrict__ d1w, const float* __restrict__ d1b,
    const float* __restrict__ d2w, const float* __restrict__ d2b,
    const float* __restrict__ g1w, const float* __restrict__ g1b,
    const float* __restrict__ g2w, const float* __restrict__ g2b,
    const float* __restrict__ fc2w, const float* __restrict__ fc2b,
    float* __restrict__ out, float* __restrict__ attn_out) {
    __shared__ float B1[16][128];
    __shared__ float B2[16][128];
    __shared__ float B3[16][128];
    __shared__ float qrow[128];
    __shared__ float resbuf[128];
    __shared__ float rel[16][4];
    __shared__ int   jidx[16];

    int n = blockIdx.x;
    int t = threadIdx.x;

    if (t < 16) jidx[t] = knn[n*16 + t];
    if (t >= 32 && t < 160) qrow[t-32] = q[(size_t)n*128 + (t-32)];
    __syncthreads();

    if (t < 48) {
        int k = t / 3, c = t % 3;
        rel[k][c] = pos[n*3 + c] - pos[(size_t)jidx[k]*3 + c];
    }
    // B1 = q - k_gather
    for (int i = t; i < 2048; i += 256) {
        int k = i >> 7, f = i & 127;
        B1[k][f] = qrow[f] - kf[(size_t)jidx[k]*128 + f];
    }
    __syncthreads();

    // B3 = hd = relu(rel @ d1 + d1b)
    for (int i = t; i < 2048; i += 256) {
        int k = i >> 7, f = i & 127;
        float v = d1b[f];
        v = fmaf(rel[k][0], d1w[f],       v);
        v = fmaf(rel[k][1], d1w[128 + f], v);
        v = fmaf(rel[k][2], d1w[256 + f], v);
        B3[k][f] = fmaxf(v, 0.0f);
    }
    __syncthreads();

    int f4 = (t & 31) * 4;
    int k0 = (t >> 5) * 2, k1 = k0 + 1;

    // pos_enc (registers): pe = hd @ d2 + d2b
    float p0[4], p1[4];
#pragma unroll
    for (int jf = 0; jf < 4; jf++) { p0[jf] = d2b[f4+jf]; p1[jf] = d2b[f4+jf]; }
    dot128x2(&B3[k0][0], &B3[k1][0], d2w, f4, p0, p1);

    // a = B1 + pe (in place) ; B2 = v_gather + pe
    {
        float v0[4], v1[4];
        *(float4*)v0 = *(const float4*)&vf[(size_t)jidx[k0]*128 + f4];
        *(float4*)v1 = *(const float4*)&vf[(size_t)jidx[k1]*128 + f4];
#pragma unroll
        for (int jf = 0; jf < 4; jf++) {
            B1[k0][f4+jf] += p0[jf];
            B1[k1][f4+jf] += p1[jf];
            B2[k0][f4+jf] = v0[jf] + p0[jf];
            B2[k1][f4+jf] = v1[jf] + p1[jf];
        }
    }
    __syncthreads();

    // B3 = gh = relu(a @ g1 + g1b)
    {
        float h0[4], h1[4];
#pragma unroll
        for (int jf = 0; jf < 4; jf++) { h0[jf] = g1b[f4+jf]; h1[jf] = g1b[f4+jf]; }
        dot128x2(&B1[k0][0], &B1[k1][0], g1w, f4, h0, h1);
        float o0[4], o1[4];
#pragma unroll
        for (int jf = 0; jf < 4; jf++) {
            o0[jf] = fmaxf(h0[jf], 0.f);
            o1[jf] = fmaxf(h1[jf], 0.f);
        }
        __syncthreads();                       // everyone done reading B3(hd)? (pe stage already was) and B1
        *(float4*)&B3[k0][f4] = *(float4*)o0;
        *(float4*)&B3[k1][f4] = *(float4*)o1;
    }
    __syncthreads();

    // gm = gh @ g2 + g2b  -> B1
    {
        float m0[4], m1[4];
#pragma unroll
        for (int jf = 0; jf < 4; jf++) { m0[jf] = g2b[f4+jf]; m1[jf] = g2b[f4+jf]; }
        dot128x2(&B3[k0][0], &B3[k1][0], g2w, f4, m0, m1);
        *(float4*)&B1[k0][f4] = *(float4*)m0;
        *(float4*)&B1[k1][f4] = *(float4*)m1;
    }
    __syncthreads();

    // softmax over K per feature; write attn; res = sum_k attn * B2
    if (t < 128) {
        int f = t;
        const float inv_s = 0.08838834764831845f;   // 1/sqrt(128)
        float l[16];
        float mx = -FLT_MAX;
#pragma unroll
        for (int k = 0; k < 16; k++) { l[k] = B1[k][f] * inv_s; mx = fmaxf(mx, l[k]); }
        float s = 0.f;
#pragma unroll
        for (int k = 0; k < 16; k++) { l[k] = expf(l[k] - mx); s += l[k]; }
        float rs = 1.0f / s;
        float r = 0.f;
#pragma unroll
        for (int k = 0; k < 16; k++) {
            float a_ = l[k] * rs;
            attn_out[((size_t)n*16 + k)*128 + f] = a_;
            r = fmaf(a_, B2[k][f], r);
        }
        resbuf[f] = r;
    }
    __syncthreads();

    // out = res @ fc2 + fc2b + x
    if (t < 64) {
        int o = t;
        float acc = fc2b[o] + x[(size_t)n*64 + o];
#pragma unroll 8
        for (int c = 0; c < 128; c++) acc = fmaf(resbuf[c], fc2w[c*64 + o], acc);
        out[(size_t)n*64 + o] = acc;
    }
}

// ---------------------------------------------------------------- launch
extern "C" void kernel_launch(void* const* d_in, const int* in_sizes, int n_in,
                              void* d_out, int out_size, void* d_ws, size_t ws_size,
                              hipStream_t stream) {
    (void)in_sizes; (void)n_in; (void)out_size; (void)ws_size;
    const float* x    = (const float*)d_in[0];
    const float* pos  = (const float*)d_in[1];
    const float* fc1w = (const float*)d_in[2];
    const float* fc1b = (const float*)d_in[3];
    const float* fc2w = (const float*)d_in[4];
    const float* fc2b = (const float*)d_in[5];
    const float* d1w  = (const float*)d_in[6];
    const float* d1b  = (const float*)d_in[7];
    const float* d2w  = (const float*)d_in[8];
    const float* d2b  = (const float*)d_in[9];
    const float* g1w  = (const float*)d_in[10];
    const float* g1b  = (const float*)d_in[11];
    const float* g2w  = (const float*)d_in[12];
    const float* g2b  = (const float*)d_in[13];
    const float* wq   = (const float*)d_in[14];
    const float* wk   = (const float*)d_in[15];
    const float* wv   = (const float*)d_in[16];

    float* out      = (float*)d_out;
    float* attn_out = out + (size_t)BN * DIN;

    float* ws = (float*)d_ws;
    float* sq = ws;
    float* q  = ws + 16384;
    float* kf = q  + (size_t)BN * DT;
    float* vf = kf + (size_t)BN * DT;
    int*  knn = (int*)(vf + (size_t)BN * DT);

    sq_kernel<<<BN/256, 256, 0, stream>>>(pos, sq);
    knn_kernel<<<BN, 64, 0, stream>>>(pos, sq, knn);
    feat_kernel<<<BN/16, 256, 0, stream>>>(x, fc1w, fc1b, wq, wk, wv, q, kf, vf);
    main_kernel<<<BN, 256, 0, stream>>>(pos, x, q, kf, vf, knn,
                                        d1w, d1b, d2w, d2b, g1w, g1b, g2w, g2b,
                                        fc2w, fc2b, out, attn_out);
}

// Round 2
// 1158.801 us; speedup vs baseline: 1.1518x; 1.1518x over previous
//
#include <hip/hip_runtime.h>
#include <float.h>

#define NPTS 4096
#define BN   16384
#define DT   128
#define DIN  64

typedef short v8s __attribute__((ext_vector_type(8)));
typedef float v4f __attribute__((ext_vector_type(4)));

__device__ __forceinline__ unsigned short f2bf(float f) {
    union { float f; unsigned u; } v; v.f = f;
    unsigned r = v.u + 0x7fff + ((v.u >> 16) & 1);
    return (unsigned short)(r >> 16);
}
__device__ __forceinline__ float bf2f(unsigned short s) {
    union { unsigned u; float f; } v; v.u = ((unsigned)s) << 16;
    return v.f;
}
__device__ __forceinline__ unsigned pack2(float lo, float hi) {
    return (unsigned)f2bf(lo) | ((unsigned)f2bf(hi) << 16);
}

// ------------------------------------------------------------------ prep
// pos4 = (x,y,z,|p|^2); wB[0..2] = d2w,g1w,g2w in B-fragment swizzled bf16;
// fc2wT[o][c] = bf16(fc2w[c][o])
__global__ __launch_bounds__(256) void prep_kernel(
    const float* __restrict__ pos, const float* __restrict__ d2w,
    const float* __restrict__ g1w, const float* __restrict__ g2w,
    const float* __restrict__ fc2w,
    float4* __restrict__ pos4, unsigned short* __restrict__ wB,
    unsigned short* __restrict__ fc2wT) {
    int i = blockIdx.x * 256 + threadIdx.x;
    if (i < BN) {
        float p0 = pos[i*3], p1 = pos[i*3+1], p2 = pos[i*3+2];
        pos4[i] = make_float4(p0, p1, p2, fmaf(p2, p2, fmaf(p1, p1, p0*p0)));
    } else if (i < BN + 3*16384) {
        int e = i - BN; int m = e >> 14; e &= 16383;
        int k = e >> 7, n = e & 127;
        const float* W = (m == 0) ? d2w : (m == 1) ? g1w : g2w;
        float val = W[k*128 + n];
        int tile = n >> 4, nl = n & 15, ks = k >> 5, q = (k >> 3) & 3, j = k & 7;
        wB[m*16384 + ((tile*4 + ks)*64 + q*16 + nl)*8 + j] = f2bf(val);
    } else if (i < BN + 3*16384 + 8192) {
        int e = i - BN - 3*16384;
        int o = e >> 7, c = e & 127;
        fc2wT[o*128 + c] = f2bf(fc2w[c*64 + o]);
    }
}

// ------------------------------------------------------------------ knn
__global__ __launch_bounds__(256, 2) void knn_kernel(const float4* __restrict__ pos4,
                                                     int* __restrict__ knnb) {
    __shared__ float sd[4096];
    __shared__ int   si[4096];
    int t = threadIdx.x;
    int lane = t & 63;
    int n = blockIdx.x * 4 + (t >> 6);
    int base = (n >> 12) << 12;
    float4 pn = pos4[n];

    float d[16]; int id[16];
#pragma unroll
    for (int i = 0; i < 16; i++) { d[i] = FLT_MAX; id[i] = 0x7fffffff; }

    for (int m = lane; m < NPTS; m += 64) {
        int j = base + m;
        float4 c = pos4[j];
        float dot  = fmaf(pn.z, c.z, fmaf(pn.y, c.y, pn.x*c.x));
        float dist = (pn.w + c.w) - 2.0f * dot;
        if (dist < d[15] || (dist == d[15] && j < id[15])) {
            float cd = dist; int ci = j;
#pragma unroll
            for (int i = 0; i < 16; i++) {
                bool lt = (cd < d[i]) || (cd == d[i] && ci < id[i]);
                float td = lt ? d[i]  : cd;  int ti = lt ? id[i] : ci;
                d[i]  = lt ? cd : d[i];
                id[i] = lt ? ci : id[i];
                cd = td; ci = ti;
            }
        }
    }

#pragma unroll
    for (int i = 0; i < 16; i++) { sd[t*16 + i] = d[i]; si[t*16 + i] = id[i]; }
    __syncthreads();

    int p = 0;
    for (int r = 0; r < 16; r++) {
        float hd = (p < 16) ? sd[t*16 + p] : FLT_MAX;
        int   hi = (p < 16) ? si[t*16 + p] : 0x7fffffff;
        float bd = hd; int bi = hi;
        for (int off = 32; off > 0; off >>= 1) {
            float od = __shfl_xor(bd, off, 64);
            int   oi = __shfl_xor(bi, off, 64);
            if (od < bd || (od == bd && oi < bi)) { bd = od; bi = oi; }
        }
        if (p < 16 && hi == bi) p++;
        if (lane == 0) knnb[n*16 + r] = bi;
    }
}

// ------------------------------------------------------------------ feat
// h = x@fc1+b ; q/k/v = h@{wq,wk,wv} -> bf16
__global__ __launch_bounds__(256) void feat_kernel(
    const float* __restrict__ x,
    const float* __restrict__ fc1w, const float* __restrict__ fc1b,
    const float* __restrict__ wq, const float* __restrict__ wk,
    const float* __restrict__ wv,
    unsigned short* __restrict__ qb, unsigned short* __restrict__ kb,
    unsigned short* __restrict__ vb) {
    __shared__ float xs[16][64];
    __shared__ float hs[16][128];
    int rb = blockIdx.x * 16;
    int t  = threadIdx.x;

    for (int i = t; i < 16*64; i += 256) xs[i>>6][i&63] = x[rb*64 + i];
    __syncthreads();

    int f4 = (t & 31) * 4;
    int r0 = (t >> 5) * 2, r1 = r0 + 1;
    float a0[4], a1[4];
#pragma unroll
    for (int jf = 0; jf < 4; jf++) { a0[jf] = fc1b[f4+jf]; a1[jf] = fc1b[f4+jf]; }
#pragma unroll 4
    for (int c = 0; c < 64; c += 4) {
        float s0[4], s1[4];
        *(float4*)s0 = *(const float4*)&xs[r0][c];
        *(float4*)s1 = *(const float4*)&xs[r1][c];
#pragma unroll
        for (int jc = 0; jc < 4; jc++) {
            float w[4];
            *(float4*)w = *(const float4*)&fc1w[(c+jc)*128 + f4];
#pragma unroll
            for (int jf = 0; jf < 4; jf++) {
                a0[jf] = fmaf(s0[jc], w[jf], a0[jf]);
                a1[jf] = fmaf(s1[jc], w[jf], a1[jf]);
            }
        }
    }
    *(float4*)&hs[r0][f4] = *(float4*)a0;
    *(float4*)&hs[r1][f4] = *(float4*)a1;
    __syncthreads();

    const float* Ws[3] = { wq, wk, wv };
    unsigned short* Os[3] = { qb, kb, vb };
    for (int mtx = 0; mtx < 3; mtx++) {
        const float* __restrict__ W = Ws[mtx];
#pragma unroll
        for (int jf = 0; jf < 4; jf++) { a0[jf] = 0.f; a1[jf] = 0.f; }
#pragma unroll 4
        for (int c = 0; c < 128; c += 4) {
            float s0[4], s1[4];
            *(float4*)s0 = *(const float4*)&hs[r0][c];
            *(float4*)s1 = *(const float4*)&hs[r1][c];
#pragma unroll
            for (int jc = 0; jc < 4; jc++) {
                float w[4];
                *(float4*)w = *(const float4*)&W[(c+jc)*128 + f4];
#pragma unroll
                for (int jf = 0; jf < 4; jf++) {
                    a0[jf] = fmaf(s0[jc], w[jf], a0[jf]);
                    a1[jf] = fmaf(s1[jc], w[jf], a1[jf]);
                }
            }
        }
        unsigned short* O = Os[mtx];
        uint2 s0v, s1v;
        s0v.x = pack2(a0[0], a0[1]); s0v.y = pack2(a0[2], a0[3]);
        s1v.x = pack2(a1[0], a1[1]); s1v.y = pack2(a1[2], a1[3]);
        *(uint2*)&O[(size_t)(rb+r0)*128 + f4] = s0v;
        *(uint2*)&O[(size_t)(rb+r1)*128 + f4] = s1v;
    }
}

// ------------------------------------------------------------------ P1
// per wave/point: hd (A-frag regs) -> pe = hd@d2+b (MFMA, C-layout regs)
// -> a_in = q-k+pe (bf16 global), vpe = v+pe (fp32, into attn region)
__global__ __launch_bounds__(256, 2) void p1_kernel(
    const float4* __restrict__ pos4, const int* __restrict__ knnb,
    const unsigned short* __restrict__ qb, const unsigned short* __restrict__ kb,
    const unsigned short* __restrict__ vb,
    const unsigned short* __restrict__ wB,
    const float* __restrict__ d1w, const float* __restrict__ d1b,
    const float* __restrict__ d2b,
    unsigned short* __restrict__ ain, float* __restrict__ vpe_out) {
    __shared__ unsigned short wBs[16384];
    int t = threadIdx.x;
    {
        const uint4* src = (const uint4*)wB;
        uint4* dst = (uint4*)wBs;
        for (int i = t; i < 2048; i += 256) dst[i] = src[i];
    }
    __syncthreads();

    int lane = t & 63, wave = t >> 6;
    int col = lane & 15, quad = lane >> 4;

    for (int it = 0; it < 4; it++) {
        int n = (blockIdx.x * 4 + wave) * 4 + it;
        int jid = knnb[n*16 + col];
        float4 pn = pos4[n];
        float4 pj = pos4[jid];
        float r0 = pn.x - pj.x, r1 = pn.y - pj.y, r2 = pn.z - pj.z;

        v8s af[4];
#pragma unroll
        for (int ks = 0; ks < 4; ks++) {
            int fb = ks*32 + quad*8;
            float w0[8], w1[8], w2[8], bb[8];
            *(float4*)&w0[0] = *(const float4*)&d1w[fb];
            *(float4*)&w0[4] = *(const float4*)&d1w[fb+4];
            *(float4*)&w1[0] = *(const float4*)&d1w[128+fb];
            *(float4*)&w1[4] = *(const float4*)&d1w[128+fb+4];
            *(float4*)&w2[0] = *(const float4*)&d1w[256+fb];
            *(float4*)&w2[4] = *(const float4*)&d1w[256+fb+4];
            *(float4*)&bb[0] = *(const float4*)&d1b[fb];
            *(float4*)&bb[4] = *(const float4*)&d1b[fb+4];
#pragma unroll
            for (int j = 0; j < 8; j++) {
                float h = fmaf(r2, w2[j], fmaf(r1, w1[j], fmaf(r0, w0[j], bb[j])));
                af[ks][j] = (short)f2bf(fmaxf(h, 0.0f));
            }
        }

        v4f acc[8];
#pragma unroll
        for (int tt = 0; tt < 8; tt++)
#pragma unroll
            for (int rr = 0; rr < 4; rr++) acc[tt][rr] = 0.0f;
#pragma unroll
        for (int ks = 0; ks < 4; ks++) {
#pragma unroll
            for (int tt = 0; tt < 8; tt++) {
                v8s b = *(const v8s*)&wBs[((tt*4 + ks) << 9) + (lane << 3)];
                acc[tt] = __builtin_amdgcn_mfma_f32_16x16x32_bf16(af[ks], b, acc[tt], 0, 0, 0);
            }
        }

#pragma unroll
        for (int tt = 0; tt < 8; tt++) {
            int cg = tt*16 + col;
            float bias = d2b[cg];
            float qv = bf2f(qb[(size_t)n*128 + cg]);
#pragma unroll
            for (int r = 0; r < 4; r++) {
                int kk = quad*4 + r;
                int jr = __shfl(jid, kk);
                float pe = acc[tt][r] + bias;
                float kv = bf2f(kb[(size_t)jr*128 + cg]);
                float vv = bf2f(vb[(size_t)jr*128 + cg]);
                float a  = qv - kv + pe;
                vpe_out[(size_t)(n*16 + kk)*128 + cg] = vv + pe;
                float o = __shfl_xor(a, 1);
                if ((lane & 1) == 0)
                    *(unsigned*)&ain[(size_t)(n*16 + kk)*128 + cg] = pack2(a, o);
            }
        }
    }
}

// ------------------------------------------------------------------ P2
// gh = relu(a_in @ g1 + g1b), in place over a_in (bf16)
__global__ __launch_bounds__(256, 2) void p2_kernel(
    unsigned short* ain, const unsigned short* __restrict__ wB,
    const float* __restrict__ g1b) {
    __shared__ unsigned short wBs[16384];
    int t = threadIdx.x;
    {
        const uint4* src = (const uint4*)(wB + 16384);
        uint4* dst = (uint4*)wBs;
        for (int i = t; i < 2048; i += 256) dst[i] = src[i];
    }
    __syncthreads();

    int lane = t & 63, wave = t >> 6;
    int col = lane & 15, quad = lane >> 4;

    for (int it = 0; it < 2; it++) {
        int rbase = ((blockIdx.x * 4 + wave) * 2 + it) * 32;
        v8s a0[4], a1[4];
#pragma unroll
        for (int ks = 0; ks < 4; ks++) {
            a0[ks] = *(const v8s*)&ain[(size_t)(rbase + col)*128 + ks*32 + quad*8];
            a1[ks] = *(const v8s*)&ain[(size_t)(rbase + 16 + col)*128 + ks*32 + quad*8];
        }
        v4f acc0[8], acc1[8];
#pragma unroll
        for (int tt = 0; tt < 8; tt++)
#pragma unroll
            for (int rr = 0; rr < 4; rr++) { acc0[tt][rr] = 0.f; acc1[tt][rr] = 0.f; }
#pragma unroll
        for (int ks = 0; ks < 4; ks++) {
#pragma unroll
            for (int tt = 0; tt < 8; tt++) {
                v8s b = *(const v8s*)&wBs[((tt*4 + ks) << 9) + (lane << 3)];
                acc0[tt] = __builtin_amdgcn_mfma_f32_16x16x32_bf16(a0[ks], b, acc0[tt], 0, 0, 0);
                acc1[tt] = __builtin_amdgcn_mfma_f32_16x16x32_bf16(a1[ks], b, acc1[tt], 0, 0, 0);
            }
        }
#pragma unroll
        for (int tt = 0; tt < 8; tt++) {
            int cg = tt*16 + col;
            float bias = g1b[cg];
#pragma unroll
            for (int r = 0; r < 4; r++) {
                float h0 = fmaxf(acc0[tt][r] + bias, 0.0f);
                float h1 = fmaxf(acc1[tt][r] + bias, 0.0f);
                float o0 = __shfl_xor(h0, 1);
                float o1 = __shfl_xor(h1, 1);
                int row0 = rbase + quad*4 + r;
                if ((lane & 1) == 0) {
                    *(unsigned*)&ain[(size_t)row0*128 + cg]      = pack2(h0, o0);
                    *(unsigned*)&ain[(size_t)(row0+16)*128 + cg] = pack2(h1, o1);
                }
            }
        }
    }
}

// ------------------------------------------------------------------ P3
// gm = gh@g2+g2b -> softmax over K -> attn write; res = sum attn*vpe;
// out = res@fc2 + fc2b + x
__global__ __launch_bounds__(256, 2) void p3_kernel(
    const unsigned short* __restrict__ gh, const unsigned short* __restrict__ wB,
    const float* __restrict__ g2b, const unsigned short* __restrict__ fc2wT,
    const float* __restrict__ fc2b, const float* __restrict__ x,
    float* __restrict__ out, float* attn) {
    __shared__ unsigned short wBs[16384];
    __shared__ float res_s[4][128];
    int t = threadIdx.x;
    {
        const uint4* src = (const uint4*)(wB + 32768);
        uint4* dst = (uint4*)wBs;
        for (int i = t; i < 2048; i += 256) dst[i] = src[i];
    }
    __syncthreads();

    int lane = t & 63, wave = t >> 6;
    int col = lane & 15, quad = lane >> 4;
    const float inv_s = 0.08838834764831845f;   // 1/sqrt(128)

    for (int it = 0; it < 4; it++) {
        int n = (blockIdx.x * 4 + wave) * 4 + it;
        v8s af[4];
#pragma unroll
        for (int ks = 0; ks < 4; ks++)
            af[ks] = *(const v8s*)&gh[(size_t)(n*16 + col)*128 + ks*32 + quad*8];
        v4f acc[8];
#pragma unroll
        for (int tt = 0; tt < 8; tt++)
#pragma unroll
            for (int rr = 0; rr < 4; rr++) acc[tt][rr] = 0.0f;
#pragma unroll
        for (int ks = 0; ks < 4; ks++) {
#pragma unroll
            for (int tt = 0; tt < 8; tt++) {
                v8s b = *(const v8s*)&wBs[((tt*4 + ks) << 9) + (lane << 3)];
                acc[tt] = __builtin_amdgcn_mfma_f32_16x16x32_bf16(af[ks], b, acc[tt], 0, 0, 0);
            }
        }

#pragma unroll
        for (int tt = 0; tt < 8; tt++) {
            int cg = tt*16 + col;
            float bias = g2b[cg];
            float l[4];
            float mx = -FLT_MAX;
#pragma unroll
            for (int r = 0; r < 4; r++) {
                l[r] = (acc[tt][r] + bias) * inv_s;
                mx = fmaxf(mx, l[r]);
            }
            mx = fmaxf(mx, __shfl_xor(mx, 16));
            mx = fmaxf(mx, __shfl_xor(mx, 32));
            float s = 0.f;
#pragma unroll
            for (int r = 0; r < 4; r++) { l[r] = __expf(l[r] - mx); s += l[r]; }
            s += __shfl_xor(s, 16);
            s += __shfl_xor(s, 32);
            float rs = 1.0f / s;
            float rp = 0.f;
            size_t base_a = (size_t)(n*16)*128 + cg;
#pragma unroll
            for (int r = 0; r < 4; r++) {
                int kk = quad*4 + r;
                float vv = attn[base_a + (size_t)kk*128];  // vpe stashed here by P1
                float av = l[r] * rs;
                rp = fmaf(av, vv, rp);
                attn[base_a + (size_t)kk*128] = av;
            }
            rp += __shfl_xor(rp, 16);
            rp += __shfl_xor(rp, 32);
            if (lane < 16) res_s[wave][cg] = rp;
        }

        // epilogue: out[n][o] = sum_c res[c]*fc2w[c][o] + fc2b[o] + x[n][o]
        int o = lane;
        float acc2 = fc2b[o] + x[(size_t)n*64 + o];
#pragma unroll
        for (int c = 0; c < 128; c += 8) {
            float4 ra = *(const float4*)&res_s[wave][c];
            float4 rb = *(const float4*)&res_s[wave][c+4];
            uint4 wr = *(const uint4*)&fc2wT[(size_t)o*128 + c];
            acc2 = fmaf(ra.x, bf2f((unsigned short)(wr.x & 0xffff)), acc2);
            acc2 = fmaf(ra.y, bf2f((unsigned short)(wr.x >> 16)),    acc2);
            acc2 = fmaf(ra.z, bf2f((unsigned short)(wr.y & 0xffff)), acc2);
            acc2 = fmaf(ra.w, bf2f((unsigned short)(wr.y >> 16)),    acc2);
            acc2 = fmaf(rb.x, bf2f((unsigned short)(wr.z & 0xffff)), acc2);
            acc2 = fmaf(rb.y, bf2f((unsigned short)(wr.z >> 16)),    acc2);
            acc2 = fmaf(rb.z, bf2f((unsigned short)(wr.w & 0xffff)), acc2);
            acc2 = fmaf(rb.w, bf2f((unsigned short)(wr.w >> 16)),    acc2);
        }
        out[(size_t)n*64 + o] = acc2;
    }
}

// ------------------------------------------------------------------ launch
extern "C" void kernel_launch(void* const* d_in, const int* in_sizes, int n_in,
                              void* d_out, int out_size, void* d_ws, size_t ws_size,
                              hipStream_t stream) {
    (void)in_sizes; (void)n_in; (void)out_size; (void)ws_size;
    const float* x    = (const float*)d_in[0];
    const float* pos  = (const float*)d_in[1];
    const float* fc1w = (const float*)d_in[2];
    const float* fc1b = (const float*)d_in[3];
    const float* fc2w = (const float*)d_in[4];
    const float* fc2b = (const float*)d_in[5];
    const float* d1w  = (const float*)d_in[6];
    const float* d1b  = (const float*)d_in[7];
    const float* d2w  = (const float*)d_in[8];
    const float* d2b  = (const float*)d_in[9];
    const float* g1w  = (const float*)d_in[10];
    const float* g1b  = (const float*)d_in[11];
    const float* g2w  = (const float*)d_in[12];
    const float* g2b  = (const float*)d_in[13];
    const float* wq   = (const float*)d_in[14];
    const float* wk   = (const float*)d_in[15];
    const float* wv   = (const float*)d_in[16];

    float* out      = (float*)d_out;
    float* attn_out = out + (size_t)BN * DIN;

    char* W = (char*)d_ws;
    float4*         pos4  = (float4*)(W + 0);                 // 256 KB
    unsigned short* wB    = (unsigned short*)(W + 262144);    // 96 KB
    unsigned short* fc2wT = (unsigned short*)(W + 360448);    // 16 KB
    int*            knnb  = (int*)(W + 376832);               // 1 MB
    unsigned short* qb    = (unsigned short*)(W + 1441792);   // 4 MB
    unsigned short* kb    = (unsigned short*)(W + 5636096);   // 4 MB
    unsigned short* vb    = (unsigned short*)(W + 9830400);   // 4 MB
    unsigned short* ain   = (unsigned short*)(W + 14024704);  // 64 MB

    prep_kernel<<<288, 256, 0, stream>>>(pos, d2w, g1w, g2w, fc2w, pos4, wB, fc2wT);
    knn_kernel<<<4096, 256, 0, stream>>>(pos4, knnb);
    feat_kernel<<<1024, 256, 0, stream>>>(x, fc1w, fc1b, wq, wk, wv, qb, kb, vb);
    p1_kernel<<<1024, 256, 0, stream>>>(pos4, knnb, qb, kb, vb, wB, d1w, d1b, d2b,
                                        ain, attn_out);
    p2_kernel<<<1024, 256, 0, stream>>>(ain, wB, g1b);
    p3_kernel<<<1024, 256, 0, stream>>>(ain, wB, g2b, fc2wT, fc2b, x, out, attn_out);
}

// Round 3
// 963.597 us; speedup vs baseline: 1.3852x; 1.2026x over previous
//
#include <hip/hip_runtime.h>
#include <float.h>

#define NPTS 4096
#define BN   16384
#define DT   128
#define DIN  64

typedef short v8s __attribute__((ext_vector_type(8)));
typedef float v4f __attribute__((ext_vector_type(4)));

__device__ __forceinline__ unsigned short f2bf(float f) {
    union { float f; unsigned u; } v; v.f = f;
    unsigned r = v.u + 0x7fff + ((v.u >> 16) & 1);
    return (unsigned short)(r >> 16);
}
__device__ __forceinline__ float bf2f(unsigned short s) {
    union { unsigned u; float f; } v; v.u = ((unsigned)s) << 16;
    return v.f;
}
__device__ __forceinline__ unsigned pack2(float lo, float hi) {
    return (unsigned)f2bf(lo) | ((unsigned)f2bf(hi) << 16);
}

// ------------------------------------------------------------------ prep
__global__ __launch_bounds__(256) void prep_kernel(
    const float* __restrict__ pos, const float* __restrict__ d2w,
    const float* __restrict__ g1w, const float* __restrict__ g2w,
    const float* __restrict__ fc2w,
    float4* __restrict__ pos4, unsigned short* __restrict__ wB,
    unsigned short* __restrict__ fc2wT) {
    int i = blockIdx.x * 256 + threadIdx.x;
    if (i < BN) {
        float p0 = pos[i*3], p1 = pos[i*3+1], p2 = pos[i*3+2];
        pos4[i] = make_float4(p0, p1, p2, fmaf(p2, p2, fmaf(p1, p1, p0*p0)));
    } else if (i < BN + 3*16384) {
        int e = i - BN; int m = e >> 14; e &= 16383;
        int k = e >> 7, n = e & 127;
        const float* W = (m == 0) ? d2w : (m == 1) ? g1w : g2w;
        float val = W[k*128 + n];
        int tile = n >> 4, nl = n & 15, ks = k >> 5, q = (k >> 3) & 3, j = k & 7;
        wB[m*16384 + ((tile*4 + ks)*64 + q*16 + nl)*8 + j] = f2bf(val);
    } else if (i < BN + 3*16384 + 8192) {
        int e = i - BN - 3*16384;
        int o = e >> 7, c = e & 127;
        fc2wT[o*128 + c] = f2bf(fc2w[c*64 + o]);
    }
}

// ------------------------------------------------------------------ knn
// Exact top-16 via threshold pruning. tau = 16th smallest of the 64 per-lane
// minima is a provable upper bound on the true 16th smallest distance; the
// candidates with dist <= tau (E[count]~18) are compacted and sorted exactly.
#define CSW(da,ia,db,ib) { bool sw_ = (da>db)||((da==db)&&(ia>ib)); \
    float td_=sw_?db:da, tD_=sw_?da:db; int ti_=sw_?ib:ia, tI_=sw_?ia:ib; \
    da=td_; db=tD_; ia=ti_; ib=tI_; }

__global__ __launch_bounds__(256, 4) void knn_kernel(const float4* __restrict__ pos4,
                                                     int* __restrict__ knnb) {
    __shared__ float scd[8][256];
    __shared__ int   sci[8][256];
    int t = threadIdx.x, lane = t & 63, w = t >> 6;
    int n0 = blockIdx.x * 8 + w * 2;     // two points per wave, same batch
    int base = n0 & ~(NPTS - 1);
    float4 pa = pos4[n0], pb = pos4[n0 + 1];

    // pass 1: per-lane minima
    float mina = FLT_MAX, minb = FLT_MAX;
    for (int m = lane; m < NPTS; m += 64) {
        float4 c = pos4[base + m];
        float da = (pa.w + c.w) - 2.0f * fmaf(pa.z, c.z, fmaf(pa.y, c.y, pa.x*c.x));
        float db = (pb.w + c.w) - 2.0f * fmaf(pb.z, c.z, fmaf(pb.y, c.y, pb.x*c.x));
        mina = fminf(mina, da); minb = fminf(minb, db);
    }
    // tau = 16th smallest lane-min (duplicate removal only enlarges tau -> still valid)
    float taua, taub;
    {
        float cur = mina;
        for (int r = 0; r < 16; r++) {
            float bd = cur;
            for (int off = 32; off; off >>= 1) bd = fminf(bd, __shfl_xor(bd, off, 64));
            taua = bd;
            if (cur == bd) cur = FLT_MAX;
        }
        cur = minb;
        for (int r = 0; r < 16; r++) {
            float bd = cur;
            for (int off = 32; off; off >>= 1) bd = fminf(bd, __shfl_xor(bd, off, 64));
            taub = bd;
            if (cur == bd) cur = FLT_MAX;
        }
    }
    // pass 2: recompute + ballot-compact candidates <= tau
    int ca = 0, cb = 0;
    for (int m = lane; m < NPTS; m += 64) {
        float4 c = pos4[base + m];
        float da = (pa.w + c.w) - 2.0f * fmaf(pa.z, c.z, fmaf(pa.y, c.y, pa.x*c.x));
        float db = (pb.w + c.w) - 2.0f * fmaf(pb.z, c.z, fmaf(pb.y, c.y, pb.x*c.x));
        bool ta = da <= taua, tb_ = db <= taub;
        unsigned long long ma = __ballot(ta), mb = __ballot(tb_);
        unsigned long long lower = (1ull << lane) - 1ull;
        if (ta) {
            int p_ = ca + __popcll(ma & lower);
            if (p_ < 256) { scd[w*2][p_] = da; sci[w*2][p_] = base + m; }
        }
        if (tb_) {
            int p_ = cb + __popcll(mb & lower);
            if (p_ < 256) { scd[w*2+1][p_] = db; sci[w*2+1][p_] = base + m; }
        }
        ca += __popcll(ma); cb += __popcll(mb);
    }
    if (ca > 256) ca = 256;
    if (cb > 256) cb = 256;
    for (int i = ca + lane; i < 256; i += 64) { scd[w*2][i]   = FLT_MAX; sci[w*2][i]   = 0x7fffffff; }
    for (int i = cb + lane; i < 256; i += 64) { scd[w*2+1][i] = FLT_MAX; sci[w*2+1][i] = 0x7fffffff; }
    __syncthreads();

    // final: per-lane sorted 4-list + 16 extraction rounds
    for (int pt = 0; pt < 2; pt++) {
        int s = w*2 + pt;
        float4 dv = *(const float4*)&scd[s][lane*4];
        int4   iv = *(const int4*)&sci[s][lane*4];
        CSW(dv.x, iv.x, dv.y, iv.y);
        CSW(dv.z, iv.z, dv.w, iv.w);
        CSW(dv.x, iv.x, dv.z, iv.z);
        CSW(dv.y, iv.y, dv.w, iv.w);
        CSW(dv.y, iv.y, dv.z, iv.z);
        int p = 0, myres = 0;
        for (int r = 0; r < 16; r++) {
            float hd = p==0 ? dv.x : p==1 ? dv.y : p==2 ? dv.z : p==3 ? dv.w : FLT_MAX;
            int   hi = p==0 ? iv.x : p==1 ? iv.y : p==2 ? iv.z : p==3 ? iv.w : 0x7fffffff;
            float bd = hd; int bi = hi;
            for (int off = 32; off; off >>= 1) {
                float od = __shfl_xor(bd, off, 64);
                int   oi = __shfl_xor(bi, off, 64);
                if (od < bd || (od == bd && oi < bi)) { bd = od; bi = oi; }
            }
            if (hi == bi) p++;
            if (lane == r) myres = bi;
        }
        if (lane < 16) knnb[(n0 + pt)*16 + lane] = myres;
    }
}

// ------------------------------------------------------------------ feat
__global__ __launch_bounds__(256) void feat_kernel(
    const float* __restrict__ x,
    const float* __restrict__ fc1w, const float* __restrict__ fc1b,
    const float* __restrict__ wq, const float* __restrict__ wk,
    const float* __restrict__ wv,
    unsigned short* __restrict__ qb, unsigned short* __restrict__ kb,
    unsigned short* __restrict__ vb) {
    __shared__ float xs[16][64];
    __shared__ float hs[16][128];
    int rb = blockIdx.x * 16;
    int t  = threadIdx.x;

    for (int i = t; i < 16*64; i += 256) xs[i>>6][i&63] = x[rb*64 + i];
    __syncthreads();

    int f4 = (t & 31) * 4;
    int r0 = (t >> 5) * 2, r1 = r0 + 1;
    float a0[4], a1[4];
#pragma unroll
    for (int jf = 0; jf < 4; jf++) { a0[jf] = fc1b[f4+jf]; a1[jf] = fc1b[f4+jf]; }
#pragma unroll 4
    for (int c = 0; c < 64; c += 4) {
        float s0[4], s1[4];
        *(float4*)s0 = *(const float4*)&xs[r0][c];
        *(float4*)s1 = *(const float4*)&xs[r1][c];
#pragma unroll
        for (int jc = 0; jc < 4; jc++) {
            float w[4];
            *(float4*)w = *(const float4*)&fc1w[(c+jc)*128 + f4];
#pragma unroll
            for (int jf = 0; jf < 4; jf++) {
                a0[jf] = fmaf(s0[jc], w[jf], a0[jf]);
                a1[jf] = fmaf(s1[jc], w[jf], a1[jf]);
            }
        }
    }
    *(float4*)&hs[r0][f4] = *(float4*)a0;
    *(float4*)&hs[r1][f4] = *(float4*)a1;
    __syncthreads();

    const float* Ws[3] = { wq, wk, wv };
    unsigned short* Os[3] = { qb, kb, vb };
    for (int mtx = 0; mtx < 3; mtx++) {
        const float* __restrict__ W = Ws[mtx];
#pragma unroll
        for (int jf = 0; jf < 4; jf++) { a0[jf] = 0.f; a1[jf] = 0.f; }
#pragma unroll 4
        for (int c = 0; c < 128; c += 4) {
            float s0[4], s1[4];
            *(float4*)s0 = *(const float4*)&hs[r0][c];
            *(float4*)s1 = *(const float4*)&hs[r1][c];
#pragma unroll
            for (int jc = 0; jc < 4; jc++) {
                float w[4];
                *(float4*)w = *(const float4*)&W[(c+jc)*128 + f4];
#pragma unroll
                for (int jf = 0; jf < 4; jf++) {
                    a0[jf] = fmaf(s0[jc], w[jf], a0[jf]);
                    a1[jf] = fmaf(s1[jc], w[jf], a1[jf]);
                }
            }
        }
        unsigned short* O = Os[mtx];
        uint2 s0v, s1v;
        s0v.x = pack2(a0[0], a0[1]); s0v.y = pack2(a0[2], a0[3]);
        s1v.x = pack2(a1[0], a1[1]); s1v.y = pack2(a1[2], a1[3]);
        *(uint2*)&O[(size_t)(rb+r0)*128 + f4] = s0v;
        *(uint2*)&O[(size_t)(rb+r1)*128 + f4] = s1v;
    }
}

// ------------------------------------------------------------------ P1
__global__ __launch_bounds__(256, 2) void p1_kernel(
    const float4* __restrict__ pos4, const int* __restrict__ knnb,
    const unsigned short* __restrict__ qb, const unsigned short* __restrict__ kb,
    const unsigned short* __restrict__ vb,
    const unsigned short* __restrict__ wB,
    const float* __restrict__ d1w, const float* __restrict__ d1b,
    const float* __restrict__ d2b,
    unsigned short* __restrict__ ain, float* __restrict__ vpe_out) {
    __shared__ unsigned short wBs[16384];
    int t = threadIdx.x;
    {
        const uint4* src = (const uint4*)wB;
        uint4* dst = (uint4*)wBs;
        for (int i = t; i < 2048; i += 256) dst[i] = src[i];
    }
    __syncthreads();

    int lane = t & 63, wave = t >> 6;
    int col = lane & 15, quad = lane >> 4;

    for (int it = 0; it < 4; it++) {
        int n = (blockIdx.x * 4 + wave) * 4 + it;
        int jid = knnb[n*16 + col];
        float4 pn = pos4[n];
        float4 pj = pos4[jid];
        float r0 = pn.x - pj.x, r1 = pn.y - pj.y, r2 = pn.z - pj.z;

        v8s af[4];
#pragma unroll
        for (int ks = 0; ks < 4; ks++) {
            int fb = ks*32 + quad*8;
            float w0[8], w1[8], w2[8], bb[8];
            *(float4*)&w0[0] = *(const float4*)&d1w[fb];
            *(float4*)&w0[4] = *(const float4*)&d1w[fb+4];
            *(float4*)&w1[0] = *(const float4*)&d1w[128+fb];
            *(float4*)&w1[4] = *(const float4*)&d1w[128+fb+4];
            *(float4*)&w2[0] = *(const float4*)&d1w[256+fb];
            *(float4*)&w2[4] = *(const float4*)&d1w[256+fb+4];
            *(float4*)&bb[0] = *(const float4*)&d1b[fb];
            *(float4*)&bb[4] = *(const float4*)&d1b[fb+4];
#pragma unroll
            for (int j = 0; j < 8; j++) {
                float h = fmaf(r2, w2[j], fmaf(r1, w1[j], fmaf(r0, w0[j], bb[j])));
                af[ks][j] = (short)f2bf(fmaxf(h, 0.0f));
            }
        }

        v4f acc[8];
#pragma unroll
        for (int tt = 0; tt < 8; tt++)
#pragma unroll
            for (int rr = 0; rr < 4; rr++) acc[tt][rr] = 0.0f;
#pragma unroll
        for (int ks = 0; ks < 4; ks++) {
#pragma unroll
            for (int tt = 0; tt < 8; tt++) {
                v8s b = *(const v8s*)&wBs[((tt*4 + ks) << 9) + (lane << 3)];
                acc[tt] = __builtin_amdgcn_mfma_f32_16x16x32_bf16(af[ks], b, acc[tt], 0, 0, 0);
            }
        }

#pragma unroll
        for (int tt = 0; tt < 8; tt++) {
            int cg = tt*16 + col;
            float bias = d2b[cg];
            float qv = bf2f(qb[(size_t)n*128 + cg]);
#pragma unroll
            for (int r = 0; r < 4; r++) {
                int kk = quad*4 + r;
                int jr = __shfl(jid, kk);
                float pe = acc[tt][r] + bias;
                float kv = bf2f(kb[(size_t)jr*128 + cg]);
                float vv = bf2f(vb[(size_t)jr*128 + cg]);
                float a  = qv - kv + pe;
                vpe_out[(size_t)(n*16 + kk)*128 + cg] = vv + pe;
                float o = __shfl_xor(a, 1);
                if ((lane & 1) == 0)
                    *(unsigned*)&ain[(size_t)(n*16 + kk)*128 + cg] = pack2(a, o);
            }
        }
    }
}

// ------------------------------------------------------------------ P23
// gh = relu(a_in@g1+b) -> LDS transpose (C-frag -> A-frag, xor-swizzled)
// -> gm = gh@g2+b -> softmax -> attn write; res = sum attn*vpe; fc2 epilogue.
__global__ __launch_bounds__(256, 2) void p23_kernel(
    const unsigned short* __restrict__ ain, const unsigned short* __restrict__ wB,
    const float* __restrict__ g1b, const float* __restrict__ g2b,
    const unsigned short* __restrict__ fc2wT, const float* __restrict__ fc2b,
    const float* __restrict__ x, float* __restrict__ out, float* attn) {
    __shared__ unsigned short g1s[16384];   // 32 KB
    __shared__ unsigned short tb[4][2048];  // 4 KB per wave: transpose buf, reused as res[]
    int t = threadIdx.x;
    {
        const uint4* src = (const uint4*)(wB + 16384);
        uint4* dst = (uint4*)g1s;
        for (int i = t; i < 2048; i += 256) dst[i] = src[i];
    }
    __syncthreads();

    const unsigned short* g2B = wB + 32768;   // read via L1/L2, 32 KB resident
    int lane = t & 63, w = t >> 6;
    int col = lane & 15, quad = lane >> 4;
    const float inv_s = 0.08838834764831845f;   // 1/sqrt(128)

    for (int it = 0; it < 4; it++) {
        int n = (blockIdx.x * 4 + w) * 4 + it;

        // A-frag of a_in
        v8s af[4];
#pragma unroll
        for (int ks = 0; ks < 4; ks++)
            af[ks] = *(const v8s*)&ain[(size_t)(n*16 + col)*128 + ks*32 + quad*8];

        v4f acc[8];
#pragma unroll
        for (int tt = 0; tt < 8; tt++)
#pragma unroll
            for (int rr = 0; rr < 4; rr++) acc[tt][rr] = 0.0f;
#pragma unroll
        for (int ks = 0; ks < 4; ks++) {
#pragma unroll
            for (int tt = 0; tt < 8; tt++) {
                v8s b = *(const v8s*)&g1s[((tt*4 + ks) << 9) + (lane << 3)];
                acc[tt] = __builtin_amdgcn_mfma_f32_16x16x32_bf16(af[ks], b, acc[tt], 0, 0, 0);
            }
        }

        // relu + pack-transpose into tb (xor-swizzled by row)
#pragma unroll
        for (int tt = 0; tt < 8; tt++) {
            float bias = g1b[tt*16 + col];
#pragma unroll
            for (int r = 0; r < 4; r++) {
                float h = fmaxf(acc[tt][r] + bias, 0.0f);
                float o = __shfl_xor(h, 1);
                if ((lane & 1) == 0) {
                    int kk = quad*4 + r;
                    int cg = tt*16 + col;
                    int idx = kk*128 + ((((cg >> 3) ^ (kk & 7))) << 3) + (cg & 7);
                    *(unsigned*)&tb[w][idx] = pack2(h, o);
                }
            }
        }
        // read back as A-frag (row m = col)
        v8s gf[4];
#pragma unroll
        for (int ks = 0; ks < 4; ks++)
            gf[ks] = *(const v8s*)&tb[w][col*128 + ((((ks*4 + quad) ^ (col & 7))) << 3)];

        v4f acc2[8];
#pragma unroll
        for (int tt = 0; tt < 8; tt++)
#pragma unroll
            for (int rr = 0; rr < 4; rr++) acc2[tt][rr] = 0.0f;
#pragma unroll
        for (int ks = 0; ks < 4; ks++) {
#pragma unroll
            for (int tt = 0; tt < 8; tt++) {
                v8s b = *(const v8s*)&g2B[((tt*4 + ks) << 9) + (lane << 3)];
                acc2[tt] = __builtin_amdgcn_mfma_f32_16x16x32_bf16(gf[ks], b, acc2[tt], 0, 0, 0);
            }
        }

        // softmax over K (rows: r in-lane, quad via xor 16/32) + attn + res
        float* resp = (float*)&tb[w][0];
#pragma unroll
        for (int tt = 0; tt < 8; tt++) {
            int cg = tt*16 + col;
            float bias = g2b[cg];
            float l[4];
            float mx = -FLT_MAX;
#pragma unroll
            for (int r = 0; r < 4; r++) {
                l[r] = (acc2[tt][r] + bias) * inv_s;
                mx = fmaxf(mx, l[r]);
            }
            mx = fmaxf(mx, __shfl_xor(mx, 16));
            mx = fmaxf(mx, __shfl_xor(mx, 32));
            float s = 0.f;
#pragma unroll
            for (int r = 0; r < 4; r++) { l[r] = __expf(l[r] - mx); s += l[r]; }
            s += __shfl_xor(s, 16);
            s += __shfl_xor(s, 32);
            float rs = 1.0f / s;
            float rp = 0.f;
            size_t base_a = (size_t)(n*16)*128 + cg;
#pragma unroll
            for (int r = 0; r < 4; r++) {
                int kk = quad*4 + r;
                float vv = attn[base_a + (size_t)kk*128];  // vpe stashed by P1
                float av = l[r] * rs;
                rp = fmaf(av, vv, rp);
                attn[base_a + (size_t)kk*128] = av;
            }
            rp += __shfl_xor(rp, 16);
            rp += __shfl_xor(rp, 32);
            if (lane < 16) resp[cg] = rp;
        }

        // epilogue: out[n][o] = res @ fc2 + fc2b + x
        int o = lane;
        float acc3 = fc2b[o] + x[(size_t)n*64 + o];
#pragma unroll
        for (int c = 0; c < 128; c += 8) {
            float4 ra = *(const float4*)&resp[c];
            float4 rb = *(const float4*)&resp[c+4];
            uint4 wr = *(const uint4*)&fc2wT[(size_t)o*128 + c];
            acc3 = fmaf(ra.x, bf2f((unsigned short)(wr.x & 0xffff)), acc3);
            acc3 = fmaf(ra.y, bf2f((unsigned short)(wr.x >> 16)),    acc3);
            acc3 = fmaf(ra.z, bf2f((unsigned short)(wr.y & 0xffff)), acc3);
            acc3 = fmaf(ra.w, bf2f((unsigned short)(wr.y >> 16)),    acc3);
            acc3 = fmaf(rb.x, bf2f((unsigned short)(wr.z & 0xffff)), acc3);
            acc3 = fmaf(rb.y, bf2f((unsigned short)(wr.z >> 16)),    acc3);
            acc3 = fmaf(rb.z, bf2f((unsigned short)(wr.w & 0xffff)), acc3);
            acc3 = fmaf(rb.w, bf2f((unsigned short)(wr.w >> 16)),    acc3);
        }
        out[(size_t)n*64 + o] = acc3;
    }
}

// ------------------------------------------------------------------ launch
extern "C" void kernel_launch(void* const* d_in, const int* in_sizes, int n_in,
                              void* d_out, int out_size, void* d_ws, size_t ws_size,
                              hipStream_t stream) {
    (void)in_sizes; (void)n_in; (void)out_size; (void)ws_size;
    const float* x    = (const float*)d_in[0];
    const float* pos  = (const float*)d_in[1];
    const float* fc1w = (const float*)d_in[2];
    const float* fc1b = (const float*)d_in[3];
    const float* fc2w = (const float*)d_in[4];
    const float* fc2b = (const float*)d_in[5];
    const float* d1w  = (const float*)d_in[6];
    const float* d1b  = (const float*)d_in[7];
    const float* d2w  = (const float*)d_in[8];
    const float* d2b  = (const float*)d_in[9];
    const float* g1w  = (const float*)d_in[10];
    const float* g1b  = (const float*)d_in[11];
    const float* g2w  = (const float*)d_in[12];
    const float* g2b  = (const float*)d_in[13];
    const float* wq   = (const float*)d_in[14];
    const float* wk   = (const float*)d_in[15];
    const float* wv   = (const float*)d_in[16];

    float* out      = (float*)d_out;
    float* attn_out = out + (size_t)BN * DIN;

    char* W = (char*)d_ws;
    float4*         pos4  = (float4*)(W + 0);                 // 256 KB
    unsigned short* wB    = (unsigned short*)(W + 262144);    // 96 KB
    unsigned short* fc2wT = (unsigned short*)(W + 360448);    // 16 KB
    int*            knnb  = (int*)(W + 376832);               // 1 MB
    unsigned short* qb    = (unsigned short*)(W + 1441792);   // 4 MB
    unsigned short* kb    = (unsigned short*)(W + 5636096);   // 4 MB
    unsigned short* vb    = (unsigned short*)(W + 9830400);   // 4 MB
    unsigned short* ain   = (unsigned short*)(W + 14024704);  // 64 MB

    prep_kernel<<<288, 256, 0, stream>>>(pos, d2w, g1w, g2w, fc2w, pos4, wB, fc2wT);
    knn_kernel<<<2048, 256, 0, stream>>>(pos4, knnb);
    feat_kernel<<<1024, 256, 0, stream>>>(x, fc1w, fc1b, wq, wk, wv, qb, kb, vb);
    p1_kernel<<<1024, 256, 0, stream>>>(pos4, knnb, qb, kb, vb, wB, d1w, d1b, d2b,
                                        ain, attn_out);
    p23_kernel<<<1024, 256, 0, stream>>>(ain, wB, g1b, g2b, fc2wT, fc2b, x, out, attn_out);
}